// Round 1
// baseline (846.746 us; speedup 1.0000x reference)
//
#include <hip/hip_runtime.h>

#define NN 100000
#define NE 1600000

// ---- workspace layout (bytes) ----
static constexpr size_t OFF_H      = 0;                                   // [N,64] f32
static constexpr size_t OFF_B      = OFF_H      + (size_t)NN * 64 * 4;    // [N,256] f32
static constexpr size_t OFF_NORM   = OFF_B      + (size_t)NN * 256 * 4;   // [N] f32
static constexpr size_t OFF_INVD   = OFF_NORM   + (size_t)NN * 4;         // [N] f32
static constexpr size_t OFF_DEG    = OFF_INVD   + (size_t)NN * 4;         // [N] i32
static constexpr size_t OFF_ROW    = OFF_DEG    + (size_t)NN * 4;         // [N+1] i32 (padded)
static constexpr size_t OFF_CUR    = OFF_ROW    + (size_t)(NN + 64) * 4;  // [N] i32
static constexpr size_t OFF_CSRC   = OFF_CUR    + (size_t)NN * 4;         // [E] i32
static constexpr size_t OFF_CSRW   = OFF_CSRC   + (size_t)NE * 4;         // [E] f32
static constexpr size_t OFF_COLSUM = OFF_CSRW   + (size_t)NE * 4;         // [256] f64

__global__ void hist_kernel(const int* __restrict__ dst, int* __restrict__ deg) {
    int i = blockIdx.x * 256 + threadIdx.x;
    if (i < NE) atomicAdd(&deg[dst[i]], 1);
}

__global__ void norm_kernel(const int* __restrict__ deg, float* __restrict__ nrm,
                            float* __restrict__ invd) {
    int i = blockIdx.x * 256 + threadIdx.x;
    if (i < NN) {
        float d = (float)max(deg[i], 1);
        nrm[i]  = 1.0f / sqrtf(d);
        invd[i] = 1.0f / d;
    }
}

// single-block scan: 1024 threads, chunks of 1024, wave-level shfl scans
__global__ void scan_kernel(const int* __restrict__ deg, int* __restrict__ row_off,
                            int* __restrict__ cursor) {
    __shared__ int wsum[16];
    __shared__ int s_carry, s_tot;
    const int tid  = threadIdx.x;
    const int lane = tid & 63;
    const int wid  = tid >> 6;
    if (tid == 0) s_carry = 0;
    __syncthreads();
    for (int base = 0; base < NN; base += 1024) {
        int i = base + tid;
        int v = (i < NN) ? deg[i] : 0;
        int x = v;
        #pragma unroll
        for (int off = 1; off < 64; off <<= 1) {
            int y = __shfl_up(x, off);
            if (lane >= off) x += y;
        }
        if (lane == 63) wsum[wid] = x;
        __syncthreads();
        if (wid == 0) {
            int w = (lane < 16) ? wsum[lane] : 0;
            #pragma unroll
            for (int off = 1; off < 16; off <<= 1) {
                int y = __shfl_up(w, off);
                if (lane >= off) w += y;
            }
            if (lane < 16) wsum[lane] = w;
            if (lane == 15) s_tot = w;
        }
        __syncthreads();
        int woff = (wid == 0) ? 0 : wsum[wid - 1];
        int excl = s_carry + woff + (x - v);
        if (i < NN) { row_off[i] = excl; cursor[i] = excl; }
        __syncthreads();
        if (tid == 0) s_carry += s_tot;
        __syncthreads();
    }
    if (tid == 0) row_off[NN] = s_carry;
}

__global__ void fill_kernel(const int* __restrict__ src, const int* __restrict__ dst,
                            const float* __restrict__ nrm, int* __restrict__ cursor,
                            int* __restrict__ csr_src, float* __restrict__ csr_w) {
    int i = blockIdx.x * 256 + threadIdx.x;
    if (i < NE) {
        int d = dst[i];
        int p = atomicAdd(&cursor[d], 1);
        int s = src[i];
        csr_src[p] = s;
        csr_w[p]   = nrm[s];
    }
}

// h = x @ W_emb.T + b_emb  (f32 VALU; W in padded LDS, x row via shfl broadcast)
__global__ void embed_kernel(const float* __restrict__ x, const float* __restrict__ W,
                             const float* __restrict__ bias, float* __restrict__ h) {
    __shared__ float Wl[64 * 65];
    const int tid  = threadIdx.x;
    const int lane = tid & 63;
    for (int i = tid; i < 64 * 64; i += 256) {
        Wl[(i >> 6) * 65 + (i & 63)] = W[i];
    }
    __syncthreads();
    float bv = bias[lane];
    const int nwaves = (gridDim.x * 256) >> 6;
    int wg = (blockIdx.x * 256 + tid) >> 6;
    for (int n = wg; n < NN; n += nwaves) {
        float xv = x[(size_t)n * 64 + lane];
        float acc = bv;
        #pragma unroll
        for (int k = 0; k < 64; ++k)
            acc = fmaf(__shfl(xv, k), Wl[lane * 65 + k], acc);
        h[(size_t)n * 64 + lane] = acc;
    }
}

// c[n,:] = inv_deg[n] * sum_{e in in(n)} h[src_e,:] * norm[src_e]
// one wave per node, lane = dim; writes unscaled c into b segment `seg`
__global__ void aggregate_kernel(const float* __restrict__ h, const int* __restrict__ row_off,
                                 const int* __restrict__ csr_src, const float* __restrict__ csr_w,
                                 const float* __restrict__ invd, float* __restrict__ b, int seg) {
    int wg   = (blockIdx.x * 256 + threadIdx.x) >> 6;
    int lane = threadIdx.x & 63;
    if (wg >= NN) return;
    int start = row_off[wg];
    int end   = row_off[wg + 1];
    float acc = 0.0f;
    for (int base = start; base < end; base += 64) {
        int cnt = min(64, end - base);
        int s = 0; float w = 0.0f;
        if (lane < cnt) { s = csr_src[base + lane]; w = csr_w[base + lane]; }
        for (int i = 0; i < cnt; ++i) {
            int   si = __shfl(s, i);
            float wi = __shfl(w, i);
            acc = fmaf(h[(size_t)si * 64 + lane], wi, acc);
        }
    }
    b[(size_t)wg * 256 + seg * 64 + lane] = acc * invd[wg];
}

// fused: bundle L2-normalize (over 64*(LAYER+2) cols) + residual h update
template <int LAYER>
__global__ void update_kernel(float* __restrict__ h, float* __restrict__ b,
                              const float* __restrict__ nrm) {
    constexpr int NSEG = LAYER + 2;
    int wg = (blockIdx.x * 256 + threadIdx.x) >> 6;
    if (wg >= NN) return;
    int lane = threadIdx.x & 63;
    float nm   = nrm[wg];
    float* brow = b + (size_t)wg * 256;
    float hval = h[(size_t)wg * 64 + lane];
    float cval = brow[(NSEG - 1) * 64 + lane];
    float vals[NSEG];
    float ss;
    if (LAYER == 0) {
        float hn = hval * nm;
        vals[0] = hn;
        vals[1] = cval;
        ss = hn * hn + cval * cval;
    } else {
        ss = cval * cval;
        #pragma unroll
        for (int j = 0; j < NSEG - 1; ++j) {
            float v = brow[j * 64 + lane];
            vals[j] = v;
            ss = fmaf(v, v, ss);
        }
        vals[NSEG - 1] = cval;
    }
    #pragma unroll
    for (int off = 32; off >= 1; off >>= 1) ss += __shfl_xor(ss, off);
    float inv = 1.0f / fmaxf(sqrtf(ss), 1e-12f);
    #pragma unroll
    for (int j = 0; j < NSEG; ++j) brow[j * 64 + lane] = vals[j] * inv;
    h[(size_t)wg * 64 + lane] = fmaf(cval, nm, hval);
}

// column sum of b [N,256] into f64[256]
__global__ void colsum_kernel(const float* __restrict__ b, double* __restrict__ cs) {
    int t = threadIdx.x;  // 256
    double acc = 0.0;
    for (int n = blockIdx.x; n < NN; n += gridDim.x)
        acc += (double)b[(size_t)n * 256 + t];
    atomicAdd(&cs[t], acc);
}

__global__ void final_kernel(const double* __restrict__ cs, const float* __restrict__ W_lin,
                             const float* __restrict__ b_lin, const float* __restrict__ W_out,
                             const float* __restrict__ b_out, float* __restrict__ out) {
    __shared__ double hg[64];
    int j = threadIdx.x;  // 64 threads
    const double invN = 1.0 / (double)NN;
    double acc = (double)b_lin[j];
    for (int k = 0; k < 256; ++k)
        acc += cs[k] * invN * (double)W_lin[j * 256 + k];
    hg[j] = acc;
    __syncthreads();
    if (j < 10) {
        double o = (double)b_out[j];
        for (int k = 0; k < 64; ++k)
            o += hg[k] * (double)W_out[j * 64 + k];
        out[j] = (float)o;
    }
}

extern "C" void kernel_launch(void* const* d_in, const int* in_sizes, int n_in,
                              void* d_out, int out_size, void* d_ws, size_t ws_size,
                              hipStream_t stream) {
    const float* x     = (const float*)d_in[0];
    const int*   src   = (const int*)d_in[1];
    const int*   dst   = (const int*)d_in[2];
    const float* W_emb = (const float*)d_in[3];
    const float* b_emb = (const float*)d_in[4];
    const float* W_lin = (const float*)d_in[5];
    const float* b_lin = (const float*)d_in[6];
    const float* W_out = (const float*)d_in[7];
    const float* b_out = (const float*)d_in[8];
    float* out = (float*)d_out;

    char* ws = (char*)d_ws;
    float*  h       = (float*)(ws + OFF_H);
    float*  b       = (float*)(ws + OFF_B);
    float*  nrm     = (float*)(ws + OFF_NORM);
    float*  invd    = (float*)(ws + OFF_INVD);
    int*    deg     = (int*)(ws + OFF_DEG);
    int*    row_off = (int*)(ws + OFF_ROW);
    int*    cursor  = (int*)(ws + OFF_CUR);
    int*    csr_src = (int*)(ws + OFF_CSRC);
    float*  csr_w   = (float*)(ws + OFF_CSRW);
    double* colsum  = (double*)(ws + OFF_COLSUM);

    hipMemsetAsync(deg, 0, (size_t)NN * 4, stream);
    hipMemsetAsync(colsum, 0, 256 * 8, stream);

    hist_kernel<<<(NE + 255) / 256, 256, 0, stream>>>(dst, deg);
    norm_kernel<<<(NN + 255) / 256, 256, 0, stream>>>(deg, nrm, invd);
    scan_kernel<<<1, 1024, 0, stream>>>(deg, row_off, cursor);
    fill_kernel<<<(NE + 255) / 256, 256, 0, stream>>>(src, dst, nrm, cursor, csr_src, csr_w);
    embed_kernel<<<512, 256, 0, stream>>>(x, W_emb, b_emb, h);

    const int nodeBlocks = (NN * 64 + 255) / 256;  // one wave per node
    // layer 0
    aggregate_kernel<<<nodeBlocks, 256, 0, stream>>>(h, row_off, csr_src, csr_w, invd, b, 1);
    update_kernel<0><<<nodeBlocks, 256, 0, stream>>>(h, b, nrm);
    // layer 1
    aggregate_kernel<<<nodeBlocks, 256, 0, stream>>>(h, row_off, csr_src, csr_w, invd, b, 2);
    update_kernel<1><<<nodeBlocks, 256, 0, stream>>>(h, b, nrm);
    // layer 2
    aggregate_kernel<<<nodeBlocks, 256, 0, stream>>>(h, row_off, csr_src, csr_w, invd, b, 3);
    update_kernel<2><<<nodeBlocks, 256, 0, stream>>>(h, b, nrm);

    colsum_kernel<<<1024, 256, 0, stream>>>(b, colsum);
    final_kernel<<<1, 64, 0, stream>>>(colsum, W_lin, b_lin, W_out, b_out, out);
}

// Round 2
// 655.498 us; speedup vs baseline: 1.2918x; 1.2918x over previous
//
#include <hip/hip_runtime.h>

#define NN 100000
#define NE 1600000
#define SCAN_BLOCKS ((NN + 255) / 256)   // 391

// ---- workspace layout (bytes) ----
static constexpr size_t OFF_H      = 0;                                   // [N,64] f32
static constexpr size_t OFF_B      = OFF_H      + (size_t)NN * 64 * 4;    // [N,256] f32
static constexpr size_t OFF_NORM   = OFF_B      + (size_t)NN * 256 * 4;   // [N] f32
static constexpr size_t OFF_INVD   = OFF_NORM   + (size_t)NN * 4;         // [N] f32
static constexpr size_t OFF_DEG    = OFF_INVD   + (size_t)NN * 4;         // [N] i32
static constexpr size_t OFF_ROW    = OFF_DEG    + (size_t)NN * 4;         // [N+1] i32 (padded)
static constexpr size_t OFF_CUR    = OFF_ROW    + (size_t)(NN + 64) * 4;  // [N] i32
static constexpr size_t OFF_BSUM   = OFF_CUR    + (size_t)NN * 4;         // [391+1] i32
static constexpr size_t OFF_BOFF   = OFF_BSUM   + (size_t)512 * 4;        // [391+1] i32
static constexpr size_t OFF_CSRC   = OFF_BOFF   + (size_t)512 * 4;        // [E] i32
static constexpr size_t OFF_PART   = OFF_CSRC   + (size_t)NE * 4;         // [512*256] f64
static constexpr size_t OFF_CS     = OFF_PART   + (size_t)512 * 256 * 8;  // [256] f64

__global__ void hist_kernel(const int* __restrict__ dst, int* __restrict__ deg) {
    int i = blockIdx.x * 256 + threadIdx.x;
    if (i < NE) atomicAdd(&deg[dst[i]], 1);
}

__global__ void norm_kernel(const int* __restrict__ deg, float* __restrict__ nrm,
                            float* __restrict__ invd) {
    int i = blockIdx.x * 256 + threadIdx.x;
    if (i < NN) {
        float d = (float)max(deg[i], 1);
        nrm[i]  = 1.0f / sqrtf(d);
        invd[i] = 1.0f / d;
    }
}

// ---- 3-stage exclusive scan of deg[NN] -> row_off/cursor ----
// stage A: per-block (256-wide) local exclusive scan into row_off, block sum into bsum
__global__ void scanA_kernel(const int* __restrict__ deg, int* __restrict__ row_off,
                             int* __restrict__ bsum) {
    __shared__ int wsum[4];
    __shared__ int wexcl[4];
    int tid = threadIdx.x, lane = tid & 63, wid = tid >> 6;
    int i = blockIdx.x * 256 + tid;
    int v = (i < NN) ? deg[i] : 0;
    int x = v;
    #pragma unroll
    for (int off = 1; off < 64; off <<= 1) {
        int y = __shfl_up(x, off);
        if (lane >= off) x += y;
    }
    if (lane == 63) wsum[wid] = x;
    __syncthreads();
    if (tid == 0) {
        int c = 0;
        #pragma unroll
        for (int j = 0; j < 4; ++j) { wexcl[j] = c; c += wsum[j]; }
        bsum[blockIdx.x] = c;
    }
    __syncthreads();
    if (i < NN) row_off[i] = (x - v) + wexcl[wid];
}

// stage B: single block scans bsum[SCAN_BLOCKS] -> boff (exclusive); writes row_off[NN]=total
__global__ void scanB_kernel(const int* __restrict__ bsum, int* __restrict__ boff,
                             int* __restrict__ row_off) {
    __shared__ int wsum[8];
    __shared__ int wexcl[8];
    __shared__ int s_tot;
    int tid = threadIdx.x, lane = tid & 63, wid = tid >> 6;  // 512 threads
    int v = (tid < SCAN_BLOCKS) ? bsum[tid] : 0;
    int x = v;
    #pragma unroll
    for (int off = 1; off < 64; off <<= 1) {
        int y = __shfl_up(x, off);
        if (lane >= off) x += y;
    }
    if (lane == 63) wsum[wid] = x;
    __syncthreads();
    if (tid == 0) {
        int c = 0;
        #pragma unroll
        for (int j = 0; j < 8; ++j) { wexcl[j] = c; c += wsum[j]; }
        s_tot = c;
    }
    __syncthreads();
    if (tid < SCAN_BLOCKS) boff[tid] = (x - v) + wexcl[wid];
    if (tid == 0) row_off[NN] = s_tot;
}

// stage C: add block offsets; init cursor
__global__ void scanC_kernel(int* __restrict__ row_off, const int* __restrict__ boff,
                             int* __restrict__ cursor) {
    int i = blockIdx.x * 256 + threadIdx.x;
    if (i < NN) {
        int r = row_off[i] + boff[blockIdx.x];
        row_off[i] = r;
        cursor[i]  = r;
    }
}

__global__ void fill_kernel(const int* __restrict__ src, const int* __restrict__ dst,
                            int* __restrict__ cursor, int* __restrict__ csr_src) {
    int i = blockIdx.x * 256 + threadIdx.x;
    if (i < NE) {
        int d = dst[i];
        int p = atomicAdd(&cursor[d], 1);
        csr_src[p] = src[i];
    }
}

// h = x @ W_emb.T + b_emb; one wave per node, 4-acc ILP
__global__ void embed_kernel(const float* __restrict__ x, const float* __restrict__ W,
                             const float* __restrict__ bias, float* __restrict__ h) {
    __shared__ float Wl[64 * 65];
    const int tid  = threadIdx.x;
    const int lane = tid & 63;
    const int wid  = tid >> 6;
    for (int i = tid; i < 64 * 64; i += 256) {
        Wl[(i >> 6) * 65 + (i & 63)] = W[i];
    }
    __syncthreads();
    float bv = bias[lane];
    const int nwaves = gridDim.x * 4;
    for (int n = blockIdx.x * 4 + wid; n < NN; n += nwaves) {
        float xv = x[(size_t)n * 64 + lane];
        float a0 = 0.f, a1 = 0.f, a2 = 0.f, a3 = 0.f;
        #pragma unroll
        for (int k = 0; k < 64; k += 4) {
            a0 = fmaf(__shfl(xv, k),     Wl[lane * 65 + k],     a0);
            a1 = fmaf(__shfl(xv, k + 1), Wl[lane * 65 + k + 1], a1);
            a2 = fmaf(__shfl(xv, k + 2), Wl[lane * 65 + k + 2], a2);
            a3 = fmaf(__shfl(xv, k + 3), Wl[lane * 65 + k + 3], a3);
        }
        h[(size_t)n * 64 + lane] = bv + ((a0 + a1) + (a2 + a3));
    }
}

// c[n,:] = inv_deg[n] * sum_{e in in(n)} h[src_e,:] * nrm[src_e]
// one wave per node, lane = dim; per-edge weight re-gathered from nrm (L2-resident)
__global__ void aggregate_kernel(const float* __restrict__ h, const int* __restrict__ row_off,
                                 const int* __restrict__ csr_src, const float* __restrict__ nrm,
                                 const float* __restrict__ invd, float* __restrict__ b, int seg) {
    int wg   = (blockIdx.x * 256 + threadIdx.x) >> 6;
    int lane = threadIdx.x & 63;
    if (wg >= NN) return;
    int start = row_off[wg];
    int end   = row_off[wg + 1];
    float a0 = 0.f, a1 = 0.f;
    for (int base = start; base < end; base += 64) {
        int cnt = min(64, end - base);
        int s = 0; float w = 0.f;
        if (lane < cnt) { s = csr_src[base + lane]; w = nrm[s]; }
        int i = 0;
        for (; i + 1 < cnt; i += 2) {
            int   s0 = __shfl(s, i),     s1 = __shfl(s, i + 1);
            float w0 = __shfl(w, i),     w1 = __shfl(w, i + 1);
            a0 = fmaf(h[(size_t)s0 * 64 + lane], w0, a0);
            a1 = fmaf(h[(size_t)s1 * 64 + lane], w1, a1);
        }
        if (i < cnt) {
            int   s0 = __shfl(s, i);
            float w0 = __shfl(w, i);
            a0 = fmaf(h[(size_t)s0 * 64 + lane], w0, a0);
        }
    }
    b[(size_t)wg * 256 + seg * 64 + lane] = (a0 + a1) * invd[wg];
}

// fused: bundle L2-normalize (over 64*(LAYER+2) cols) + residual h update
template <int LAYER>
__global__ void update_kernel(float* __restrict__ h, float* __restrict__ b,
                              const float* __restrict__ nrm) {
    constexpr int NSEG = LAYER + 2;
    int wg = (blockIdx.x * 256 + threadIdx.x) >> 6;
    if (wg >= NN) return;
    int lane = threadIdx.x & 63;
    float nm   = nrm[wg];
    float* brow = b + (size_t)wg * 256;
    float cval = brow[(NSEG - 1) * 64 + lane];
    float vals[NSEG];
    float ss;
    float hval = 0.f;
    if (LAYER == 0) {
        hval = h[(size_t)wg * 64 + lane];
        float hn = hval * nm;
        vals[0] = hn;
        vals[1] = cval;
        ss = hn * hn + cval * cval;
    } else {
        if (LAYER < 2) hval = h[(size_t)wg * 64 + lane];
        ss = cval * cval;
        #pragma unroll
        for (int j = 0; j < NSEG - 1; ++j) {
            float v = brow[j * 64 + lane];
            vals[j] = v;
            ss = fmaf(v, v, ss);
        }
        vals[NSEG - 1] = cval;
    }
    #pragma unroll
    for (int off = 32; off >= 1; off >>= 1) ss += __shfl_xor(ss, off);
    float inv = 1.0f / fmaxf(sqrtf(ss), 1e-12f);
    #pragma unroll
    for (int j = 0; j < NSEG; ++j) brow[j * 64 + lane] = vals[j] * inv;
    if (LAYER < 2) {
        if (LAYER == 0) {
            h[(size_t)wg * 64 + lane] = fmaf(cval, nm, hval);
        } else {
            h[(size_t)wg * 64 + lane] = fmaf(cval, nm, hval);
        }
    }
    // note: LAYER==2 skips the h update (h unused afterwards)
}

// column sum of b [N,256]: stage 1 -> partial[512][256] (f64), no atomics
__global__ void colsum1_kernel(const float* __restrict__ b, double* __restrict__ partial) {
    int t = threadIdx.x;  // 256
    double acc = 0.0;
    for (int n = blockIdx.x; n < NN; n += gridDim.x)
        acc += (double)b[(size_t)n * 256 + t];
    partial[(size_t)blockIdx.x * 256 + t] = acc;
}

// stage 2: reduce 512 partials per column
__global__ void colsum2_kernel(const double* __restrict__ partial, double* __restrict__ cs) {
    int t = threadIdx.x;  // 256
    double acc = 0.0;
    for (int j = 0; j < 512; ++j) acc += partial[(size_t)j * 256 + t];
    cs[t] = acc;
}

__global__ void final_kernel(const double* __restrict__ cs, const float* __restrict__ W_lin,
                             const float* __restrict__ b_lin, const float* __restrict__ W_out,
                             const float* __restrict__ b_out, float* __restrict__ out) {
    __shared__ double hg[64];
    int j = threadIdx.x;  // 64 threads
    const double invN = 1.0 / (double)NN;
    double acc = (double)b_lin[j];
    for (int k = 0; k < 256; ++k)
        acc += cs[k] * invN * (double)W_lin[j * 256 + k];
    hg[j] = acc;
    __syncthreads();
    if (j < 10) {
        double o = (double)b_out[j];
        for (int k = 0; k < 64; ++k)
            o += hg[k] * (double)W_out[j * 64 + k];
        out[j] = (float)o;
    }
}

extern "C" void kernel_launch(void* const* d_in, const int* in_sizes, int n_in,
                              void* d_out, int out_size, void* d_ws, size_t ws_size,
                              hipStream_t stream) {
    const float* x     = (const float*)d_in[0];
    const int*   src   = (const int*)d_in[1];
    const int*   dst   = (const int*)d_in[2];
    const float* W_emb = (const float*)d_in[3];
    const float* b_emb = (const float*)d_in[4];
    const float* W_lin = (const float*)d_in[5];
    const float* b_lin = (const float*)d_in[6];
    const float* W_out = (const float*)d_in[7];
    const float* b_out = (const float*)d_in[8];
    float* out = (float*)d_out;

    char* ws = (char*)d_ws;
    float*  h       = (float*)(ws + OFF_H);
    float*  b       = (float*)(ws + OFF_B);
    float*  nrm     = (float*)(ws + OFF_NORM);
    float*  invd    = (float*)(ws + OFF_INVD);
    int*    deg     = (int*)(ws + OFF_DEG);
    int*    row_off = (int*)(ws + OFF_ROW);
    int*    cursor  = (int*)(ws + OFF_CUR);
    int*    bsum    = (int*)(ws + OFF_BSUM);
    int*    boff    = (int*)(ws + OFF_BOFF);
    int*    csr_src = (int*)(ws + OFF_CSRC);
    double* partial = (double*)(ws + OFF_PART);
    double* cs      = (double*)(ws + OFF_CS);

    hipMemsetAsync(deg, 0, (size_t)NN * 4, stream);

    hist_kernel<<<(NE + 255) / 256, 256, 0, stream>>>(dst, deg);
    norm_kernel<<<SCAN_BLOCKS, 256, 0, stream>>>(deg, nrm, invd);
    scanA_kernel<<<SCAN_BLOCKS, 256, 0, stream>>>(deg, row_off, bsum);
    scanB_kernel<<<1, 512, 0, stream>>>(bsum, boff, row_off);
    scanC_kernel<<<SCAN_BLOCKS, 256, 0, stream>>>(row_off, boff, cursor);
    fill_kernel<<<(NE + 255) / 256, 256, 0, stream>>>(src, dst, cursor, csr_src);
    embed_kernel<<<2048, 256, 0, stream>>>(x, W_emb, b_emb, h);

    const int nodeBlocks = (NN * 64 + 255) / 256;  // one wave per node
    // layer 0
    aggregate_kernel<<<nodeBlocks, 256, 0, stream>>>(h, row_off, csr_src, nrm, invd, b, 1);
    update_kernel<0><<<nodeBlocks, 256, 0, stream>>>(h, b, nrm);
    // layer 1
    aggregate_kernel<<<nodeBlocks, 256, 0, stream>>>(h, row_off, csr_src, nrm, invd, b, 2);
    update_kernel<1><<<nodeBlocks, 256, 0, stream>>>(h, b, nrm);
    // layer 2
    aggregate_kernel<<<nodeBlocks, 256, 0, stream>>>(h, row_off, csr_src, nrm, invd, b, 3);
    update_kernel<2><<<nodeBlocks, 256, 0, stream>>>(h, b, nrm);

    colsum1_kernel<<<512, 256, 0, stream>>>(b, partial);
    colsum2_kernel<<<1, 256, 0, stream>>>(partial, cs);
    final_kernel<<<1, 64, 0, stream>>>(cs, W_lin, b_lin, W_out, b_out, out);
}

// Round 3
// 503.571 us; speedup vs baseline: 1.6815x; 1.3017x over previous
//
#include <hip/hip_runtime.h>

#define NN 100000
#define NE 1600000

// ---- workspace layout (bytes) ----
// persistent
static constexpr size_t OFF_H0   = 0;                    // [N,64] f32
static constexpr size_t OFF_H1   = 25600000;             // [N,64] f32 (later reused as c2*g2)
static constexpr size_t OFF_H2   = 51200000;             // [N,64] f32
static constexpr size_t OFF_CSR  = 76800000;             // [E] i32
static constexpr size_t OFF_ROW  = 83200000;             // [N+1] i32
static constexpr size_t OFF_NRM  = 83600016;             // [N] f32
static constexpr size_t OFF_INVD = 84000016;             // [N] f32
static constexpr size_t OFF_HH   = 84400016;             // [N] f32 (later g0)
static constexpr size_t OFF_Q0   = 84800016;             // [N] f32 (later g1)
static constexpr size_t OFF_Q1   = 85200016;             // [N] f32
static constexpr size_t OFF_SCR  = 85600016;             // union scratch base
// scratch A (CSR build, dead after merge)
static constexpr size_t OFF_SUBDEG = OFF_SCR;            // [8N] i32
static constexpr size_t OFF_SUBROW = OFF_SCR + 3200000;  // [8N+1] i32
static constexpr size_t OFF_SUBCUR = OFF_SCR + 6400016;  // [8N] i32
static constexpr size_t OFF_SUBCSR = OFF_SCR + 9600016;  // [E] i32
static constexpr size_t OFF_DEG    = OFF_SCR + 16000016; // [N] i32
static constexpr size_t OFF_BSUM   = OFF_SCR + 16400016; // [<=1568] i32
static constexpr size_t OFF_BOFF   = OFF_SCR + 16406288; // [<=1568] i32
// scratch B (layers onward)
static constexpr size_t OFF_C0    = OFF_SCR;             // [N,64] f32
static constexpr size_t OFF_C1    = OFF_SCR + 25600000;  // [N,64] f32
static constexpr size_t OFF_PARTF = OFF_SCR + 51200000;  // [1024,256] f64
static constexpr size_t OFF_MID   = OFF_SCR + 53297152;  // [32,256] f64

// ---- CSR build: XCD-local sub-CSRs ----
__global__ void hist8_kernel(const int* __restrict__ dst, int* __restrict__ subdeg) {
    int e = blockIdx.x * 256 + threadIdx.x;
    int g = blockIdx.x & 7;
    if (e < NE) {
        int d = __builtin_nontemporal_load(&dst[e]);
        atomicAdd(&subdeg[g * NN + d], 1);
    }
}

__global__ void degnorm_kernel(const int* __restrict__ subdeg, int* __restrict__ deg,
                               float* __restrict__ nrm, float* __restrict__ invd) {
    int n = blockIdx.x * 256 + threadIdx.x;
    if (n < NN) {
        int d = 0;
        #pragma unroll
        for (int g = 0; g < 8; ++g) d += subdeg[g * NN + n];
        deg[n] = d;
        float df = (float)max(d, 1);
        nrm[n]  = 1.0f / sqrtf(df);
        invd[n] = 1.0f / df;
    }
}

// ---- generic 3-stage exclusive scan (512-thread blocks) ----
__global__ void scanA_kernel(const int* __restrict__ in, int n, int* __restrict__ outloc,
                             int* __restrict__ bsum) {
    __shared__ int wsum[8], wexcl[8];
    int tid = threadIdx.x, lane = tid & 63, wid = tid >> 6;
    int i = blockIdx.x * 512 + tid;
    int v = (i < n) ? in[i] : 0;
    int x = v;
    #pragma unroll
    for (int off = 1; off < 64; off <<= 1) {
        int y = __shfl_up(x, off);
        if (lane >= off) x += y;
    }
    if (lane == 63) wsum[wid] = x;
    __syncthreads();
    if (tid == 0) {
        int c = 0;
        #pragma unroll
        for (int j = 0; j < 8; ++j) { wexcl[j] = c; c += wsum[j]; }
        bsum[blockIdx.x] = c;
    }
    __syncthreads();
    if (i < n) outloc[i] = (x - v) + wexcl[wid];
}

__global__ void scanB_kernel(const int* __restrict__ bsum, int nb, int* __restrict__ boff,
                             int* __restrict__ total_out) {
    __shared__ int wsum[8], wexcl[8];
    __shared__ int carry;
    int tid = threadIdx.x, lane = tid & 63, wid = tid >> 6;
    if (tid == 0) carry = 0;
    __syncthreads();
    for (int base = 0; base < nb; base += 512) {
        int i = base + tid;
        int v = (i < nb) ? bsum[i] : 0;
        int x = v;
        #pragma unroll
        for (int off = 1; off < 64; off <<= 1) {
            int y = __shfl_up(x, off);
            if (lane >= off) x += y;
        }
        if (lane == 63) wsum[wid] = x;
        __syncthreads();
        if (tid == 0) {
            int c = 0;
            #pragma unroll
            for (int j = 0; j < 8; ++j) { wexcl[j] = c; c += wsum[j]; }
        }
        __syncthreads();
        if (i < nb) boff[i] = carry + wexcl[wid] + (x - v);
        __syncthreads();
        if (tid == 0) carry += wexcl[7] + wsum[7];
        __syncthreads();
    }
    if (tid == 0) *total_out = carry;
}

__global__ void scanC_kernel(int* __restrict__ outloc, const int* __restrict__ boff, int n,
                             int* __restrict__ copy) {
    int i = blockIdx.x * 512 + threadIdx.x;
    if (i < n) {
        int r = outloc[i] + boff[blockIdx.x];
        outloc[i] = r;
        if (copy) copy[i] = r;
    }
}

__global__ void fillB_kernel(const int* __restrict__ src, const int* __restrict__ dst,
                             int* __restrict__ subcur, int* __restrict__ subcsr) {
    int e = blockIdx.x * 256 + threadIdx.x;
    int g = blockIdx.x & 7;
    if (e < NE) {
        int d = __builtin_nontemporal_load(&dst[e]);
        int s = __builtin_nontemporal_load(&src[e]);
        int p = atomicAdd(&subcur[g * NN + d], 1);
        subcsr[p] = s;
    }
}

// concatenate the 8 sub-segments of each node into the global CSR
__global__ void merge_kernel(const int* __restrict__ row_off, const int* __restrict__ subrow,
                             const int* __restrict__ subcur, const int* __restrict__ subcsr,
                             int* __restrict__ csr_src) {
    int n = blockIdx.x * 256 + threadIdx.x;
    if (n >= NN) return;
    int q = row_off[n];
    #pragma unroll
    for (int g = 0; g < 8; ++g) {
        int i = g * NN + n;
        int st = subrow[i], en = subcur[i];
        for (int k = st; k < en; ++k) csr_src[q++] = subcsr[k];
    }
}

// ---- embed: h0 = x @ W_emb.T + b_emb ----
__global__ void embed_kernel(const float* __restrict__ x, const float* __restrict__ W,
                             const float* __restrict__ bias, float* __restrict__ h) {
    __shared__ float Wl[64 * 65];
    const int tid  = threadIdx.x;
    const int lane = tid & 63;
    const int wid  = tid >> 6;
    for (int i = tid; i < 64 * 64; i += 256) Wl[(i >> 6) * 65 + (i & 63)] = W[i];
    __syncthreads();
    float bv = bias[lane];
    const int nwaves = gridDim.x * 4;
    for (int n = blockIdx.x * 4 + wid; n < NN; n += nwaves) {
        float xv = x[(size_t)n * 64 + lane];
        float a0 = 0.f, a1 = 0.f, a2 = 0.f, a3 = 0.f;
        #pragma unroll
        for (int k = 0; k < 64; k += 4) {
            a0 = fmaf(__shfl(xv, k),     Wl[lane * 65 + k],     a0);
            a1 = fmaf(__shfl(xv, k + 1), Wl[lane * 65 + k + 1], a1);
            a2 = fmaf(__shfl(xv, k + 2), Wl[lane * 65 + k + 2], a2);
            a3 = fmaf(__shfl(xv, k + 3), Wl[lane * 65 + k + 3], a3);
        }
        h[(size_t)n * 64 + lane] = bv + ((a0 + a1) + (a2 + a3));
    }
}

__device__ __forceinline__ float gather_row(const float* __restrict__ h,
                                            const int* __restrict__ csr_src,
                                            const float* __restrict__ nrm,
                                            int start, int end, int lane) {
    float a0 = 0.f, a1 = 0.f;
    for (int base = start; base < end; base += 64) {
        int cnt = min(64, end - base);
        int s = 0; float w = 0.f;
        if (lane < cnt) { s = csr_src[base + lane]; w = nrm[s]; }
        int i = 0;
        for (; i + 1 < cnt; i += 2) {
            int   s0 = __shfl(s, i),     s1 = __shfl(s, i + 1);
            float w0 = __shfl(w, i),     w1 = __shfl(w, i + 1);
            a0 = fmaf(h[(size_t)s0 * 64 + lane], w0, a0);
            a1 = fmaf(h[(size_t)s1 * 64 + lane], w1, a1);
        }
        if (i < cnt) {
            int s0 = __shfl(s, i); float w0 = __shfl(w, i);
            a0 = fmaf(h[(size_t)s0 * 64 + lane], w0, a0);
        }
    }
    return a0 + a1;
}

__global__ void layer0_kernel(const float* __restrict__ h0, const int* __restrict__ row_off,
                              const int* __restrict__ csr_src, const float* __restrict__ nrm,
                              const float* __restrict__ invd, float* __restrict__ c0,
                              float* __restrict__ h1, float* __restrict__ hh,
                              float* __restrict__ q0) {
    int wg = (blockIdx.x * 256 + threadIdx.x) >> 6;
    int lane = threadIdx.x & 63;
    if (wg >= NN) return;
    float cv = gather_row(h0, csr_src, nrm, row_off[wg], row_off[wg + 1], lane) * invd[wg];
    float nm = nrm[wg];
    size_t o = (size_t)wg * 64 + lane;
    float hv = h0[o];
    float hn = hv * nm;
    c0[o] = cv;
    h1[o] = fmaf(cv, nm, hv);
    float sh = hn * hn, sc = cv * cv;
    #pragma unroll
    for (int off = 32; off >= 1; off >>= 1) {
        sh += __shfl_xor(sh, off);
        sc += __shfl_xor(sc, off);
    }
    if (lane == 0) { hh[wg] = sh; q0[wg] = sc; }
}

__global__ void layer1_kernel(const float* __restrict__ h1, const int* __restrict__ row_off,
                              const int* __restrict__ csr_src, const float* __restrict__ nrm,
                              const float* __restrict__ invd, float* __restrict__ c1,
                              float* __restrict__ h2, float* __restrict__ q1) {
    int wg = (blockIdx.x * 256 + threadIdx.x) >> 6;
    int lane = threadIdx.x & 63;
    if (wg >= NN) return;
    float cv = gather_row(h1, csr_src, nrm, row_off[wg], row_off[wg + 1], lane) * invd[wg];
    float nm = nrm[wg];
    size_t o = (size_t)wg * 64 + lane;
    float hv = h1[o];
    c1[o] = cv;
    h2[o] = fmaf(cv, nm, hv);
    float sc = cv * cv;
    #pragma unroll
    for (int off = 32; off >= 1; off >>= 1) sc += __shfl_xor(sc, off);
    if (lane == 0) q1[wg] = sc;
}

// layer2: gather c2, compute full scalar chain, store c2*g2 (into dead h1 buffer),
// overwrite hh<-g0, q0<-g1
__global__ void layer2_kernel(const float* __restrict__ h2, const int* __restrict__ row_off,
                              const int* __restrict__ csr_src, const float* __restrict__ nrm,
                              const float* __restrict__ invd, float* __restrict__ hh,
                              float* __restrict__ q0, const float* __restrict__ q1,
                              float* __restrict__ c2g) {
    int wg = (blockIdx.x * 256 + threadIdx.x) >> 6;
    int lane = threadIdx.x & 63;
    if (wg >= NN) return;
    float cv = gather_row(h2, csr_src, nrm, row_off[wg], row_off[wg + 1], lane) * invd[wg];
    float q2 = cv * cv;
    #pragma unroll
    for (int off = 32; off >= 1; off >>= 1) q2 += __shfl_xor(q2, off);
    float hh0 = hh[wg], q0v = q0[wg], q1v = q1[wg];
    const float EPS = 1e-12f;
    float n0s = hh0 + q0v;
    float s0 = fmaxf(sqrtf(n0s), EPS);
    float r1s = n0s / (s0 * s0) + q1v;
    float s1 = fmaxf(sqrtf(r1s), EPS);
    float r2s = r1s / (s1 * s1) + q2;
    float s2 = fmaxf(sqrtf(r2s), EPS);
    float g2 = 1.0f / s2;
    float g1 = 1.0f / (s1 * s2);
    float g0 = g1 / s0;
    c2g[(size_t)wg * 64 + lane] = cv * g2;
    if (lane == 0) { hh[wg] = g0; q0[wg] = g1; }
}

// weighted column sums of the final bundle, fixed-order f64 partials
__global__ void colsum_final(const float* __restrict__ h0, const float* __restrict__ c0,
                             const float* __restrict__ c1, const float* __restrict__ c2g,
                             const float* __restrict__ nrm, const float* __restrict__ g0a,
                             const float* __restrict__ g1a, double* __restrict__ partialF) {
    __shared__ double lds[256];
    int tid = threadIdx.x, lane = tid & 63, wid = tid >> 6;
    double a0 = 0.0, a1 = 0.0, a2 = 0.0, a3 = 0.0;
    for (int n = blockIdx.x * 4 + wid; n < NN; n += gridDim.x * 4) {
        float nm = nrm[n], g0 = g0a[n], g1 = g1a[n];
        size_t o = (size_t)n * 64 + lane;
        float hn = h0[o] * nm;
        a0 += (double)(hn * g0);
        a1 += (double)(c0[o] * g0);
        a2 += (double)(c1[o] * g1);
        a3 += (double)c2g[o];
    }
    #pragma unroll
    for (int seg = 0; seg < 4; ++seg) {
        double v = (seg == 0) ? a0 : (seg == 1) ? a1 : (seg == 2) ? a2 : a3;
        lds[tid] = v;
        __syncthreads();
        if (wid == 0)
            partialF[(size_t)blockIdx.x * 256 + seg * 64 + lane] =
                lds[lane] + lds[64 + lane] + lds[128 + lane] + lds[192 + lane];
        __syncthreads();
    }
}

__global__ void reduceP_kernel(const double* __restrict__ partialF, double* __restrict__ mid) {
    int t = threadIdx.x;
    double acc = 0.0;
    for (int j = 0; j < 32; ++j)
        acc += partialF[((size_t)blockIdx.x * 32 + j) * 256 + t];
    mid[(size_t)blockIdx.x * 256 + t] = acc;
}

__global__ void final_kernel(const double* __restrict__ mid, const float* __restrict__ W_lin,
                             const float* __restrict__ b_lin, const float* __restrict__ W_out,
                             const float* __restrict__ b_out, float* __restrict__ out) {
    __shared__ double cs[256];
    __shared__ double hg[64];
    int t = threadIdx.x;  // 256
    double acc = 0.0;
    for (int b = 0; b < 32; ++b) acc += mid[b * 256 + t];
    cs[t] = acc;
    __syncthreads();
    if (t < 64) {
        const double invN = 1.0 / (double)NN;
        double a = (double)b_lin[t];
        for (int k = 0; k < 256; ++k) a += cs[k] * invN * (double)W_lin[t * 256 + k];
        hg[t] = a;
    }
    __syncthreads();
    if (t < 10) {
        double o = (double)b_out[t];
        for (int k = 0; k < 64; ++k) o += hg[k] * (double)W_out[t * 64 + k];
        out[t] = (float)o;
    }
}

extern "C" void kernel_launch(void* const* d_in, const int* in_sizes, int n_in,
                              void* d_out, int out_size, void* d_ws, size_t ws_size,
                              hipStream_t stream) {
    const float* x     = (const float*)d_in[0];
    const int*   src   = (const int*)d_in[1];
    const int*   dst   = (const int*)d_in[2];
    const float* W_emb = (const float*)d_in[3];
    const float* b_emb = (const float*)d_in[4];
    const float* W_lin = (const float*)d_in[5];
    const float* b_lin = (const float*)d_in[6];
    const float* W_out = (const float*)d_in[7];
    const float* b_out = (const float*)d_in[8];
    float* out = (float*)d_out;

    char* ws = (char*)d_ws;
    float*  h0      = (float*)(ws + OFF_H0);
    float*  h1      = (float*)(ws + OFF_H1);
    float*  h2      = (float*)(ws + OFF_H2);
    int*    csr_src = (int*)(ws + OFF_CSR);
    int*    row_off = (int*)(ws + OFF_ROW);
    float*  nrm     = (float*)(ws + OFF_NRM);
    float*  invd    = (float*)(ws + OFF_INVD);
    float*  hh      = (float*)(ws + OFF_HH);
    float*  q0      = (float*)(ws + OFF_Q0);
    float*  q1      = (float*)(ws + OFF_Q1);
    int*    subdeg  = (int*)(ws + OFF_SUBDEG);
    int*    subrow  = (int*)(ws + OFF_SUBROW);
    int*    subcur  = (int*)(ws + OFF_SUBCUR);
    int*    subcsr  = (int*)(ws + OFF_SUBCSR);
    int*    deg     = (int*)(ws + OFF_DEG);
    int*    bsum    = (int*)(ws + OFF_BSUM);
    int*    boff    = (int*)(ws + OFF_BOFF);
    float*  c0      = (float*)(ws + OFF_C0);
    float*  c1      = (float*)(ws + OFF_C1);
    double* partialF= (double*)(ws + OFF_PARTF);
    double* mid     = (double*)(ws + OFF_MID);

    hipMemsetAsync(subdeg, 0, (size_t)8 * NN * 4, stream);

    const int edgeBlocks = (NE + 255) / 256;            // 6250
    hist8_kernel<<<edgeBlocks, 256, 0, stream>>>(dst, subdeg);
    degnorm_kernel<<<(NN + 255) / 256, 256, 0, stream>>>(subdeg, deg, nrm, invd);

    // scan subdeg[8N] -> subrow (+ copy to subcur)
    const int sb8 = (8 * NN + 511) / 512;               // 1563
    scanA_kernel<<<sb8, 512, 0, stream>>>(subdeg, 8 * NN, subrow, bsum);
    scanB_kernel<<<1, 512, 0, stream>>>(bsum, sb8, boff, subrow + 8 * NN);
    scanC_kernel<<<sb8, 512, 0, stream>>>(subrow, boff, 8 * NN, subcur);
    // scan deg[N] -> row_off
    const int sbN = (NN + 511) / 512;                   // 196
    scanA_kernel<<<sbN, 512, 0, stream>>>(deg, NN, row_off, bsum);
    scanB_kernel<<<1, 512, 0, stream>>>(bsum, sbN, boff, row_off + NN);
    scanC_kernel<<<sbN, 512, 0, stream>>>(row_off, boff, NN, (int*)nullptr);

    fillB_kernel<<<edgeBlocks, 256, 0, stream>>>(src, dst, subcur, subcsr);
    merge_kernel<<<(NN + 255) / 256, 256, 0, stream>>>(row_off, subrow, subcur, subcsr, csr_src);

    embed_kernel<<<2048, 256, 0, stream>>>(x, W_emb, b_emb, h0);

    const int nodeBlocks = (NN * 64 + 255) / 256;       // wave per node
    layer0_kernel<<<nodeBlocks, 256, 0, stream>>>(h0, row_off, csr_src, nrm, invd, c0, h1, hh, q0);
    layer1_kernel<<<nodeBlocks, 256, 0, stream>>>(h1, row_off, csr_src, nrm, invd, c1, h2, q1);
    layer2_kernel<<<nodeBlocks, 256, 0, stream>>>(h2, row_off, csr_src, nrm, invd, hh, q0, q1, h1);

    colsum_final<<<1024, 256, 0, stream>>>(h0, c0, c1, h1, nrm, hh, q0, partialF);
    reduceP_kernel<<<32, 256, 0, stream>>>(partialF, mid);
    final_kernel<<<1, 256, 0, stream>>>(mid, W_lin, b_lin, W_out, b_out, out);
}